// Round 6
// baseline (663.710 us; speedup 1.0000x reference)
//
#include <hip/hip_runtime.h>
#include <math.h>

#define NN 100000
#define ND 1000000
#define INDIM 133
#define K1P 160                 // padded input dim (5 x 32)
#define NCNT (2*NN)
#define SCAN_CHUNK 2048
#define NBLK_SCAN ((NCNT + SCAN_CHUNK - 1) / SCAN_CHUNK)
#define HS 72                   // LDS h-tile row stride in bf16 elems (144B)

typedef __bf16 bf16x8 __attribute__((ext_vector_type(8)));
typedef __bf16 bf16x4 __attribute__((ext_vector_type(4)));
typedef float  f32x4  __attribute__((ext_vector_type(4)));
typedef _Float16 f16;
typedef _Float16 f16x4 __attribute__((ext_vector_type(4)));

__device__ __forceinline__ f32x4 mfma_bf16(bf16x8 a, bf16x8 b, f32x4 c) {
    return __builtin_amdgcn_mfma_f32_16x16x32_bf16(a, b, c, 0, 0, 0);
}

__device__ __forceinline__ float3 f3sub(float3 a, float3 b) {
    return make_float3(a.x - b.x, a.y - b.y, a.z - b.z);
}
__device__ __forceinline__ float3 f3cross(float3 a, float3 b) {
    return make_float3(a.y * b.z - a.z * b.y, a.z * b.x - a.x * b.z, a.x * b.y - a.y * b.x);
}
__device__ __forceinline__ float f3dot(float3 a, float3 b) {
    return a.x * b.x + a.y * b.y + a.z * b.z;
}
__device__ __forceinline__ float3 f3load(const float* __restrict__ p, int idx) {
    const float* q = p + (size_t)idx * 3;
    return make_float3(q[0], q[1], q[2]);
}
__device__ __forceinline__ float fsilu(float v) {
    return v / (1.0f + __expf(-v));
}

// ---- per-node prep: split raw x to bf16 hi/lo, per-node LN stats (S, Q) ----
__global__ __launch_bounds__(256) void prep_xtab(const float* __restrict__ x,
                                                 __bf16* __restrict__ xh,
                                                 __bf16* __restrict__ xl,
                                                 float2* __restrict__ sq) {
    const int n = blockIdx.x * 4 + (threadIdx.x >> 6);
    const int c = threadIdx.x & 63;
    float v = x[(size_t)n * 64 + c];
    float s = v, q = v * v;
#pragma unroll
    for (int d = 1; d < 64; d <<= 1) {
        s += __shfl_xor(s, d);
        q += __shfl_xor(q, d);
    }
    if (c == 0) sq[n] = make_float2(s, q);
    __bf16 h = (__bf16)v;
    xh[(size_t)n * 64 + c] = h;
    xl[(size_t)n * 64 + c] = (__bf16)(v - (float)h);
}

// ---- w1g = diag(gamma) @ w1, transposed [n][k], padded, split hi/lo ----
__global__ __launch_bounds__(256) void prep_w1g(const float* __restrict__ w1,
                                                const float* __restrict__ gamma,
                                                __bf16* __restrict__ hi,
                                                __bf16* __restrict__ lo) {
    int idx = blockIdx.x * 256 + threadIdx.x;
    if (idx >= 64 * K1P) return;
    int n = idx / K1P, kp = idx - n * K1P;
    float v = (kp < INDIM) ? gamma[kp] * w1[(size_t)kp * 64 + n] : 0.0f;
    __bf16 h = (__bf16)v;
    hi[idx] = h;
    lo[idx] = (__bf16)(v - (float)h);
}

// ---- c1 = gamma @ w1, d1 = beta @ w1 + b1 (f32 epilogue constants) ----
__global__ __launch_bounds__(64) void prep_lin(const float* __restrict__ w1,
                                               const float* __restrict__ b1,
                                               const float* __restrict__ gamma,
                                               const float* __restrict__ beta,
                                               float* __restrict__ c1,
                                               float* __restrict__ d1) {
    const int c = threadIdx.x;
    float sc = 0.0f, sd = 0.0f;
    for (int k = 0; k < INDIM; ++k) {
        float w = w1[(size_t)k * 64 + c];
        sc = fmaf(gamma[k], w, sc);
        sd = fmaf(beta[k], w, sd);
    }
    c1[c] = sc;
    d1[c] = sd + b1[c];
}

// ---- w2: transpose to [n][k'], k' in PERMUTED h-space (k'=4m+nt <-> k=16nt+m) ----
__global__ __launch_bounds__(256) void prep_w(const float* __restrict__ w,
                                              __bf16* __restrict__ hi,
                                              __bf16* __restrict__ lo) {
    int idx = blockIdx.x * 256 + threadIdx.x;
    if (idx >= 64 * 64) return;
    int n = idx >> 6, kp = idx & 63;
    int ko = 16 * (kp & 3) + (kp >> 2);
    float v = w[(size_t)ko * 64 + n];
    __bf16 h = (__bf16)v;
    hi[idx] = h;
    lo[idx] = (__bf16)(v - (float)h);
}

// ---- w3'' = (w3 @ w_out) * 2^-4 folded, transposed [c][k'], permuted ----
__global__ __launch_bounds__(256) void prep_w3(const float* __restrict__ w3,
                                               const float* __restrict__ b3,
                                               const float* __restrict__ wout,
                                               __bf16* __restrict__ hiT,
                                               __bf16* __restrict__ loT,
                                               float* __restrict__ b3f) {
    const int tid = threadIdx.x;
    for (int idx = tid; idx < 64 * 64; idx += 256) {
        int k = idx >> 6, c = idx & 63;
        float s = 0.0f;
        for (int q = 0; q < 64; ++q)
            s = fmaf(w3[(size_t)k * 64 + q], wout[(size_t)q * 64 + c], s);
        s *= 0.0625f;
        __bf16 h = (__bf16)s;
        int kp = 4 * (k & 15) + (k >> 4);
        hiT[(size_t)c * 64 + kp] = h;
        loT[(size_t)c * 64 + kp] = (__bf16)(s - (float)h);
    }
    if (tid < 64) {
        float s = 0.0f;
        for (int q = 0; q < 64; ++q)
            s = fmaf(b3[q], wout[(size_t)q * 64 + tid], s);
        b3f[tid] = s * 0.0625f;
    }
}

// ---- counting sort ----
__global__ __launch_bounds__(256) void count_kernel(const int* __restrict__ qidx,
                                                    int* __restrict__ cnt) {
    int e = blockIdx.x * 256 + threadIdx.x;
    if (e < ND) {
        atomicAdd(&cnt[qidx[ND + e]], 1);
        atomicAdd(&cnt[NN + qidx[2 * ND + e]], 1);
    }
}

__global__ __launch_bounds__(256) void scan1(int* data, int* __restrict__ bsum) {
    __shared__ int lds[256];
    const int tid = threadIdx.x;
    const int base = blockIdx.x * SCAN_CHUNK + tid * 8;
    int v[8];
    int tsum = 0;
#pragma unroll
    for (int t = 0; t < 8; ++t) {
        v[t] = (base + t < NCNT) ? data[base + t] : 0;
        tsum += v[t];
    }
    lds[tid] = tsum;
    __syncthreads();
    for (int d = 1; d < 256; d <<= 1) {
        int t = 0;
        if (tid >= d) t = lds[tid - d];
        __syncthreads();
        lds[tid] += t;
        __syncthreads();
    }
    if (tid == 255) bsum[blockIdx.x] = lds[255];
    int run = lds[tid] - tsum;
#pragma unroll
    for (int t = 0; t < 8; ++t) {
        if (base + t < NCNT) data[base + t] = run;
        run += v[t];
    }
}

__global__ __launch_bounds__(128) void scan2(int* __restrict__ bsum) {
    __shared__ int lds[128];
    const int t = threadIdx.x;
    int v = (t < NBLK_SCAN) ? bsum[t] : 0;
    lds[t] = v;
    __syncthreads();
    for (int d = 1; d < 128; d <<= 1) {
        int u = (t >= d) ? lds[t - d] : 0;
        __syncthreads();
        lds[t] += u;
        __syncthreads();
    }
    if (t < NBLK_SCAN) bsum[t] = lds[t] - v;
}

__global__ __launch_bounds__(256) void scan3(int* __restrict__ off,
                                             const int* __restrict__ bsum) {
    const int base = blockIdx.x * SCAN_CHUNK + threadIdx.x * 8;
    const int add = bsum[blockIdx.x];
#pragma unroll
    for (int t = 0; t < 8; ++t) {
        int i = base + t;
        if (i < NCNT) off[i] += add;
    }
}

// fill: list[slot] = edge id; afterwards off[b] = END of bucket b
__global__ __launch_bounds__(256) void fill_kernel(const int* __restrict__ qidx,
                                                   int* __restrict__ off,
                                                   int* __restrict__ list) {
    int e = blockIdx.x * 256 + threadIdx.x;
    if (e < ND) {
        int s1 = atomicAdd(&off[qidx[ND + e]], 1);
        list[s1] = e;
        int s2 = atomicAdd(&off[NN + qidx[2 * ND + e]], 1);
        list[s2] = e;
    }
}

// ---- edge MLP: 32 edges/wave, A-frags streamed straight from pre-split tables,
// LN folded into f32 epilogue (stats from per-node S,Q), coalesced single msg write ----
__global__ __launch_bounds__(256, 3) void edge_mlp_mfma(
    const __bf16* __restrict__ xh, const __bf16* __restrict__ xlo,
    const float2* __restrict__ sq, const float* __restrict__ pos,
    const int* __restrict__ qidx, const float* __restrict__ qattr,
    const float* __restrict__ gamma,
    const __bf16* __restrict__ w1h, const __bf16* __restrict__ w1l,
    const float* __restrict__ c1, const float* __restrict__ d1,
    const __bf16* __restrict__ w2h, const __bf16* __restrict__ w2l, const float* __restrict__ b2,
    const __bf16* __restrict__ w3h, const __bf16* __restrict__ w3l, const float* __restrict__ b3f,
    f16* __restrict__ msg)
{
    __shared__ __align__(16) __bf16 hsh[4][2][16 * HS];

    const int tid = threadIdx.x;
    const int w   = tid >> 6;
    const int l   = tid & 63;
    const int m   = l & 15;
    const int kg  = l >> 4;
    const int ebase = (blockIdx.x * 4 + w) * 32;
    if (ebase >= ND) return;               // no barriers: early-out safe

    // A-row indices for both tiles
    int iA[2], lA[2];
#pragma unroll
    for (int t = 0; t < 2; ++t) {
        const int e = ebase + 16 * t + m;
        iA[t] = qidx[e];
        lA[t] = qidx[3 * ND + e];
    }

    // ---- dihedral + raw-extras stats: tile kg on lanes kg<2 ----
    float cosd = 0.f, sind = 0.f, at0 = 0.f, at1 = 0.f, at2 = 0.f, se = 0.f, qe = 0.f;
    if (kg < 2) {
        const int e2 = ebase + 16 * kg + m;
        const int j2 = qidx[ND + e2];
        const int k2 = qidx[2 * ND + e2];
        float3 pi = f3load(pos, iA[kg]), pj = f3load(pos, j2);
        float3 pk = f3load(pos, k2), pl = f3load(pos, lA[kg]);
        float3 d1v_ = f3sub(pj, pi);
        float3 d2v_ = f3sub(pk, pj);
        float3 d3v_ = f3sub(pl, pk);
        float3 n1 = f3cross(d1v_, d2v_);
        float3 n2 = f3cross(d2v_, d3v_);
        float r1 = 1.0f / fmaxf(sqrtf(f3dot(n1, n1)), 1e-6f);
        n1.x *= r1; n1.y *= r1; n1.z *= r1;
        float r2 = 1.0f / fmaxf(sqrtf(f3dot(n2, n2)), 1e-6f);
        n2.x *= r2; n2.y *= r2; n2.z *= r2;
        cosd = fminf(fmaxf(f3dot(n1, n2), -1.0f), 1.0f);
        float rb = 1.0f / fmaxf(sqrtf(f3dot(d2v_, d2v_)), 1e-6f);
        float3 b2n = make_float3(d2v_.x * rb, d2v_.y * rb, d2v_.z * rb);
        float3 mm = f3cross(n1, b2n);
        sind = f3dot(mm, n2);
        at0 = qattr[(size_t)e2 * 3 + 0];
        at1 = qattr[(size_t)e2 * 3 + 1];
        at2 = qattr[(size_t)e2 * 3 + 2];
        se = at0 + at1 + at2 + cosd + sind;                      // raw extras sum
        qe = at0 * at0 + at1 * at1 + at2 * at2 + cosd * cosd + sind * sind;
    }

    const float g128 = gamma[128], g129 = gamma[129], g130 = gamma[130];
    const float g131 = gamma[131], g132 = gamma[132];

    // per-tile LN stats + gamma-scaled extras A-frags
    float rs_[2], mn_[2];
    bf16x8 ah4[2], al4[2];
#pragma unroll
    for (int t = 0; t < 2; ++t) {
        const int src = m + 16 * t;
        float ct  = __shfl(cosd, src), st = __shfl(sind, src);
        float a0t = __shfl(at0, src), a1t = __shfl(at1, src), a2t = __shfl(at2, src);
        float set = __shfl(se, src),  qet = __shfl(qe, src);
        float2 si = sq[iA[t]], sl = sq[lA[t]];
        float S = si.x + sl.x + set;
        float Q = si.y + sl.y + qet;
        float mu  = S * (1.0f / INDIM);
        float var = Q * (1.0f / INDIM) - mu * mu;
        float rsv = rsqrtf(fmaxf(var, 0.0f) + 1e-5f);
        rs_[t] = rsv;
        mn_[t] = -mu * rsv;
        float g0 = (kg == 0) ? 1.0f : 0.0f;
        float u4[8] = {a0t * g128 * g0, a1t * g129 * g0, a2t * g130 * g0,
                       ct * g131 * g0, st * g132 * g0, 0.f, 0.f, 0.f};
#pragma unroll
        for (int j = 0; j < 8; ++j) {
            __bf16 h = (__bf16)u4[j];
            ah4[t][j] = h;
            al4[t][j] = (__bf16)(u4[j] - (float)h);
        }
    }

    // ---- layer 1: P = raw_x @ w1g (+ extras), split 3-MFMA, A streamed from tables ----
    f32x4 acc[2][4];
#pragma unroll
    for (int t = 0; t < 2; ++t)
#pragma unroll
        for (int nt = 0; nt < 4; ++nt) acc[t][nt] = (f32x4){0.f, 0.f, 0.f, 0.f};

    // extras slice first (retires ah4/al4 early)
#pragma unroll
    for (int nt = 0; nt < 4; ++nt) {
        const size_t wb = (size_t)(16 * nt + m) * K1P + 128 + 8 * kg;
        bf16x8 bh = *(const bf16x8*)(w1h + wb);
        bf16x8 bl = *(const bf16x8*)(w1l + wb);
        acc[0][nt] = mfma_bf16(ah4[0], bh, acc[0][nt]);
        acc[0][nt] = mfma_bf16(al4[0], bh, acc[0][nt]);
        acc[0][nt] = mfma_bf16(ah4[0], bl, acc[0][nt]);
        acc[1][nt] = mfma_bf16(ah4[1], bh, acc[1][nt]);
        acc[1][nt] = mfma_bf16(al4[1], bh, acc[1][nt]);
        acc[1][nt] = mfma_bf16(ah4[1], bl, acc[1][nt]);
    }
#pragma unroll
    for (int s = 0; s < 4; ++s) {
        const int r0 = (s < 2) ? iA[0] : lA[0];
        const int r1 = (s < 2) ? iA[1] : lA[1];
        const int colo = 32 * (s & 1) + 8 * kg;
        bf16x8 a0h = *(const bf16x8*)(xh  + (size_t)r0 * 64 + colo);
        bf16x8 a0l = *(const bf16x8*)(xlo + (size_t)r0 * 64 + colo);
        bf16x8 a1h = *(const bf16x8*)(xh  + (size_t)r1 * 64 + colo);
        bf16x8 a1l = *(const bf16x8*)(xlo + (size_t)r1 * 64 + colo);
#pragma unroll
        for (int nt = 0; nt < 4; ++nt) {
            const size_t wb = (size_t)(16 * nt + m) * K1P + 32 * s + 8 * kg;
            bf16x8 bh = *(const bf16x8*)(w1h + wb);
            bf16x8 bl = *(const bf16x8*)(w1l + wb);
            acc[0][nt] = mfma_bf16(a0h, bh, acc[0][nt]);
            acc[0][nt] = mfma_bf16(a0l, bh, acc[0][nt]);
            acc[0][nt] = mfma_bf16(a0h, bl, acc[0][nt]);
            acc[1][nt] = mfma_bf16(a1h, bh, acc[1][nt]);
            acc[1][nt] = mfma_bf16(a1l, bh, acc[1][nt]);
            acc[1][nt] = mfma_bf16(a1h, bl, acc[1][nt]);
        }
    }

    // epilogue 1: h1 = silu(rs*P + (-rs*mu)*c1 + d1), permuted-col 8B LDS stores
    float c1v[4], d1v[4], b2v[4], b3v[4];
#pragma unroll
    for (int nt = 0; nt < 4; ++nt) {
        c1v[nt] = c1[16 * nt + m];
        d1v[nt] = d1[16 * nt + m];
        b2v[nt] = b2[16 * nt + m];
        b3v[nt] = b3f[16 * nt + m];
    }
#pragma unroll
    for (int t = 0; t < 2; ++t) {
        __bf16* hhw = &hsh[w][t][0];
#pragma unroll
        for (int r = 0; r < 4; ++r) {
            float rse = __shfl(rs_[t], 4 * kg + r);
            float mne = __shfl(mn_[t], 4 * kg + r);
            bf16x4 hv4;
#pragma unroll
            for (int nt = 0; nt < 4; ++nt)
                hv4[nt] = (__bf16)fsilu(fmaf(rse, acc[t][nt][r],
                                        fmaf(mne, c1v[nt], d1v[nt])));
            *(bf16x4*)(hhw + (4 * kg + r) * HS + m * 4) = hv4;
        }
    }

    // ---- layer 2: hi-A x split-W ----
    bf16x8 a2h[2][2];
#pragma unroll
    for (int t = 0; t < 2; ++t)
#pragma unroll
        for (int s = 0; s < 2; ++s)
            a2h[t][s] = *(const bf16x8*)(&hsh[w][t][m * HS + 32 * s + 8 * kg]);
    f32x4 acc2[2][4];
#pragma unroll
    for (int t = 0; t < 2; ++t)
#pragma unroll
        for (int nt = 0; nt < 4; ++nt) acc2[t][nt] = (f32x4){0.f, 0.f, 0.f, 0.f};
#pragma unroll
    for (int s = 0; s < 2; ++s) {
#pragma unroll
        for (int nt = 0; nt < 4; ++nt) {
            const size_t wb = (size_t)(16 * nt + m) * 64 + 32 * s + 8 * kg;
            bf16x8 bh = *(const bf16x8*)(w2h + wb);
            bf16x8 bl = *(const bf16x8*)(w2l + wb);
            acc2[0][nt] = mfma_bf16(a2h[0][s], bh, acc2[0][nt]);
            acc2[0][nt] = mfma_bf16(a2h[0][s], bl, acc2[0][nt]);
            acc2[1][nt] = mfma_bf16(a2h[1][s], bh, acc2[1][nt]);
            acc2[1][nt] = mfma_bf16(a2h[1][s], bl, acc2[1][nt]);
        }
    }
#pragma unroll
    for (int t = 0; t < 2; ++t) {
        __bf16* hhw = &hsh[w][t][0];
#pragma unroll
        for (int r = 0; r < 4; ++r) {
            bf16x4 hv4;
#pragma unroll
            for (int nt = 0; nt < 4; ++nt)
                hv4[nt] = (__bf16)fsilu(acc2[t][nt][r] + b2v[nt]);
            *(bf16x4*)(hhw + (4 * kg + r) * HS + m * 4) = hv4;
        }
    }

    // ---- layer 3 (w_out + scale folded) ----
    bf16x8 a3h[2][2];
#pragma unroll
    for (int t = 0; t < 2; ++t)
#pragma unroll
        for (int s = 0; s < 2; ++s)
            a3h[t][s] = *(const bf16x8*)(&hsh[w][t][m * HS + 32 * s + 8 * kg]);
    f32x4 acc3[2][4];
#pragma unroll
    for (int t = 0; t < 2; ++t)
#pragma unroll
        for (int nt = 0; nt < 4; ++nt) acc3[t][nt] = (f32x4){0.f, 0.f, 0.f, 0.f};
#pragma unroll
    for (int s = 0; s < 2; ++s) {
#pragma unroll
        for (int nt = 0; nt < 4; ++nt) {
            const size_t wb = (size_t)(16 * nt + m) * 64 + 32 * s + 8 * kg;
            bf16x8 bh = *(const bf16x8*)(w3h + wb);
            bf16x8 bl = *(const bf16x8*)(w3l + wb);
            acc3[0][nt] = mfma_bf16(a3h[0][s], bh, acc3[0][nt]);
            acc3[0][nt] = mfma_bf16(a3h[0][s], bl, acc3[0][nt]);
            acc3[1][nt] = mfma_bf16(a3h[1][s], bh, acc3[1][nt]);
            acc3[1][nt] = mfma_bf16(a3h[1][s], bl, acc3[1][nt]);
        }
    }

    // ---- msg: single coalesced edge-order write (permuted cols, f16x4) ----
#pragma unroll
    for (int t = 0; t < 2; ++t) {
#pragma unroll
        for (int r = 0; r < 4; ++r) {
            f16x4 v;
#pragma unroll
            for (int nt = 0; nt < 4; ++nt)
                v[nt] = (f16)(acc3[t][nt][r] + b3v[nt]);
            const int er = ebase + 16 * t + 4 * kg + r;
            *(f16x4*)(msg + (size_t)er * 64 + m * 4) = v;
        }
    }
}

// ---- node aggregation: gather rows by sorted list (msg is L3-resident) ----
__global__ __launch_bounds__(256) void node_out(const f16* __restrict__ msg,
                                                const int* __restrict__ off,
                                                const int* __restrict__ list,
                                                float* __restrict__ out) {
    const int w   = threadIdx.x >> 6;
    const int l   = threadIdx.x & 63;
    const int sub = l >> 4;
    const int m16 = l & 15;
    for (int n = blockIdx.x * 4 + w; n < NN; n += gridDim.x * 4) {
        int ja = (n == 0) ? 0 : off[n - 1];
        int jb = off[n];
        int ka = off[NN + n - 1];   // n==0 -> off[NN-1] = start of k-region
        int kb = off[NN + n];
        float s0 = 0.f, s1 = 0.f, s2 = 0.f, s3 = 0.f;
        float t0 = 0.f, t1 = 0.f, t2 = 0.f, t3 = 0.f;
        for (int p = ja + sub; p < jb; p += 4) {
            int e = list[p];
            f16x4 v = *(const f16x4*)(msg + (size_t)e * 64 + m16 * 4);
            s0 += (float)v[0]; s1 += (float)v[1];
            s2 += (float)v[2]; s3 += (float)v[3];
        }
        for (int p = ka + sub; p < kb; p += 4) {
            int e = list[p];
            f16x4 v = *(const f16x4*)(msg + (size_t)e * 64 + m16 * 4);
            t0 += (float)v[0]; t1 += (float)v[1];
            t2 += (float)v[2]; t3 += (float)v[3];
        }
        s0 += __shfl_xor(s0, 16); s0 += __shfl_xor(s0, 32);
        s1 += __shfl_xor(s1, 16); s1 += __shfl_xor(s1, 32);
        s2 += __shfl_xor(s2, 16); s2 += __shfl_xor(s2, 32);
        s3 += __shfl_xor(s3, 16); s3 += __shfl_xor(s3, 32);
        t0 += __shfl_xor(t0, 16); t0 += __shfl_xor(t0, 32);
        t1 += __shfl_xor(t1, 16); t1 += __shfl_xor(t1, 32);
        t2 += __shfl_xor(t2, 16); t2 += __shfl_xor(t2, 32);
        t3 += __shfl_xor(t3, 16); t3 += __shfl_xor(t3, 32);
        if (sub == 0) {
            float rj = 1.0f / fmaxf((float)(jb - ja), 1.0f);
            float rk = 1.0f / fmaxf((float)(kb - ka), 1.0f);
            float* o = out + (size_t)n * 64;
            o[m16]      = s0 * rj + t0 * rk;   // col' 4m+nt <-> true col 16nt+m
            o[16 + m16] = s1 * rj + t1 * rk;
            o[32 + m16] = s2 * rj + t2 * rk;
            o[48 + m16] = s3 * rj + t3 * rk;
        }
    }
}

// ============================ launch ============================

extern "C" void kernel_launch(void* const* d_in, const int* in_sizes, int n_in,
                              void* d_out, int out_size, void* d_ws, size_t ws_size,
                              hipStream_t stream) {
    (void)in_sizes; (void)n_in; (void)out_size;

    const float* x     = (const float*)d_in[0];
    const float* pos   = (const float*)d_in[1];
    const int*   qidx  = (const int*)d_in[2];
    const float* qattr = (const float*)d_in[3];
    const float* gamma = (const float*)d_in[4];
    const float* beta  = (const float*)d_in[5];
    const float* w1    = (const float*)d_in[6];
    const float* b1    = (const float*)d_in[7];
    const float* w2    = (const float*)d_in[8];
    const float* b2    = (const float*)d_in[9];
    const float* w3    = (const float*)d_in[10];
    const float* b3    = (const float*)d_in[11];
    const float* w_out = (const float*)d_in[12];
    float* out = (float*)d_out;

    size_t o = 0;
    auto alloc = [&](size_t bytes) { size_t r = o; o = (o + bytes + 255) & ~(size_t)255; return r; };
    char* W = (char*)d_ws;
    f16*    msg  = (f16*)   (W + alloc((size_t)ND * 64 * sizeof(f16)));       // 128 MB
    int*    list = (int*)   (W + alloc((size_t)2 * ND * sizeof(int)));        // 8 MB
    int*    off  = (int*)   (W + alloc((size_t)NCNT * sizeof(int)));
    int*    bsum = (int*)   (W + alloc((size_t)NBLK_SCAN * sizeof(int)));
    __bf16* xh   = (__bf16*)(W + alloc((size_t)NN * 64 * sizeof(__bf16)));    // 12.8 MB
    __bf16* xlo  = (__bf16*)(W + alloc((size_t)NN * 64 * sizeof(__bf16)));    // 12.8 MB
    float2* sqt  = (float2*)(W + alloc((size_t)NN * sizeof(float2)));
    __bf16* w1h  = (__bf16*)(W + alloc((size_t)64 * K1P * sizeof(__bf16)));
    __bf16* w1l  = (__bf16*)(W + alloc((size_t)64 * K1P * sizeof(__bf16)));
    __bf16* w2h  = (__bf16*)(W + alloc((size_t)64 * 64 * sizeof(__bf16)));
    __bf16* w2l  = (__bf16*)(W + alloc((size_t)64 * 64 * sizeof(__bf16)));
    __bf16* w3h  = (__bf16*)(W + alloc((size_t)64 * 64 * sizeof(__bf16)));
    __bf16* w3l  = (__bf16*)(W + alloc((size_t)64 * 64 * sizeof(__bf16)));
    float*  c1   = (float*) (W + alloc((size_t)64 * sizeof(float)));
    float*  d1   = (float*) (W + alloc((size_t)64 * sizeof(float)));
    float*  b3f  = (float*) (W + alloc((size_t)64 * sizeof(float)));
    if (ws_size < o) return;   // ~163 MB total

    // prep
    prep_xtab<<<NN / 4, 256, 0, stream>>>(x, xh, xlo, sqt);
    prep_w1g<<<(64 * K1P + 255) / 256, 256, 0, stream>>>(w1, gamma, w1h, w1l);
    prep_lin<<<1, 64, 0, stream>>>(w1, b1, gamma, beta, c1, d1);
    prep_w<<<16, 256, 0, stream>>>(w2, w2h, w2l);
    prep_w3<<<1, 256, 0, stream>>>(w3, b3, w_out, w3h, w3l, b3f);

    // counting sort
    hipMemsetAsync(off, 0, (size_t)NCNT * sizeof(int), stream);
    count_kernel<<<(ND + 255) / 256, 256, 0, stream>>>(qidx, off);
    scan1<<<NBLK_SCAN, 256, 0, stream>>>(off, bsum);
    scan2<<<1, 128, 0, stream>>>(bsum);
    scan3<<<NBLK_SCAN, 256, 0, stream>>>(off, bsum);
    fill_kernel<<<(ND + 255) / 256, 256, 0, stream>>>(qidx, off, list);

    // edge MLP -> msg (edge order, coalesced)
    edge_mlp_mfma<<<(ND + 127) / 128, 256, 0, stream>>>(xh, xlo, sqt, pos, qidx, qattr,
                                                        gamma, w1h, w1l, c1, d1,
                                                        w2h, w2l, b2, w3h, w3l, b3f, msg);
    // node aggregation (gather by sorted list)
    node_out<<<4096, 256, 0, stream>>>(msg, off, list, out);
}

// Round 7
// 595.892 us; speedup vs baseline: 1.1138x; 1.1138x over previous
//
#include <hip/hip_runtime.h>
#include <math.h>

#define NN 100000
#define ND 1000000
#define INDIM 133
#define K1P 160                 // padded input dim (5 x 32)
#define NCNT (2*NN)
#define SCAN_CHUNK 2048
#define NBLK_SCAN ((NCNT + SCAN_CHUNK - 1) / SCAN_CHUNK)
#define HS 72                   // LDS h-tile row stride in bf16 elems (144B)

typedef __bf16 bf16x8 __attribute__((ext_vector_type(8)));
typedef __bf16 bf16x4 __attribute__((ext_vector_type(4)));
typedef float  f32x4  __attribute__((ext_vector_type(4)));
typedef _Float16 f16;
typedef _Float16 f16x4 __attribute__((ext_vector_type(4)));

__device__ __forceinline__ f32x4 mfma_bf16(bf16x8 a, bf16x8 b, f32x4 c) {
    return __builtin_amdgcn_mfma_f32_16x16x32_bf16(a, b, c, 0, 0, 0);
}

__device__ __forceinline__ float3 f3sub(float3 a, float3 b) {
    return make_float3(a.x - b.x, a.y - b.y, a.z - b.z);
}
__device__ __forceinline__ float3 f3cross(float3 a, float3 b) {
    return make_float3(a.y * b.z - a.z * b.y, a.z * b.x - a.x * b.z, a.x * b.y - a.y * b.x);
}
__device__ __forceinline__ float f3dot(float3 a, float3 b) {
    return a.x * b.x + a.y * b.y + a.z * b.z;
}
__device__ __forceinline__ float3 f3load(const float* __restrict__ p, int idx) {
    const float* q = p + (size_t)idx * 3;
    return make_float3(q[0], q[1], q[2]);
}
__device__ __forceinline__ float fsilu(float v) {
    return v / (1.0f + __expf(-v));
}

// ---- w1g = diag(gamma) @ w1, transposed [n][k], padded, split hi/lo ----
__global__ __launch_bounds__(256) void prep_w1g(const float* __restrict__ w1,
                                                const float* __restrict__ gamma,
                                                __bf16* __restrict__ hi,
                                                __bf16* __restrict__ lo) {
    int idx = blockIdx.x * 256 + threadIdx.x;
    if (idx >= 64 * K1P) return;
    int n = idx / K1P, kp = idx - n * K1P;
    float v = (kp < INDIM) ? gamma[kp] * w1[(size_t)kp * 64 + n] : 0.0f;
    __bf16 h = (__bf16)v;
    hi[idx] = h;
    lo[idx] = (__bf16)(v - (float)h);
}

// ---- c1 = gamma @ w1, d1 = beta @ w1 + b1 (f32 epilogue constants) ----
__global__ __launch_bounds__(64) void prep_lin(const float* __restrict__ w1,
                                               const float* __restrict__ b1,
                                               const float* __restrict__ gamma,
                                               const float* __restrict__ beta,
                                               float* __restrict__ c1,
                                               float* __restrict__ d1) {
    const int c = threadIdx.x;
    float sc = 0.0f, sd = 0.0f;
    for (int k = 0; k < INDIM; ++k) {
        float w = w1[(size_t)k * 64 + c];
        sc = fmaf(gamma[k], w, sc);
        sd = fmaf(beta[k], w, sd);
    }
    c1[c] = sc;
    d1[c] = sd + b1[c];
}

// ---- w2: transpose to [n][k'], k' in PERMUTED h-space (k'=4m+nt <-> k=16nt+m) ----
__global__ __launch_bounds__(256) void prep_w(const float* __restrict__ w,
                                              __bf16* __restrict__ hi,
                                              __bf16* __restrict__ lo) {
    int idx = blockIdx.x * 256 + threadIdx.x;
    if (idx >= 64 * 64) return;
    int n = idx >> 6, kp = idx & 63;
    int ko = 16 * (kp & 3) + (kp >> 2);
    float v = w[(size_t)ko * 64 + n];
    __bf16 h = (__bf16)v;
    hi[idx] = h;
    lo[idx] = (__bf16)(v - (float)h);
}

// ---- w3'' = (w3 @ w_out) * 2^-4 folded, transposed [c][k'], permuted ----
__global__ __launch_bounds__(256) void prep_w3(const float* __restrict__ w3,
                                               const float* __restrict__ b3,
                                               const float* __restrict__ wout,
                                               __bf16* __restrict__ hiT,
                                               __bf16* __restrict__ loT,
                                               float* __restrict__ b3f) {
    const int tid = threadIdx.x;
    for (int idx = tid; idx < 64 * 64; idx += 256) {
        int k = idx >> 6, c = idx & 63;
        float s = 0.0f;
        for (int q = 0; q < 64; ++q)
            s = fmaf(w3[(size_t)k * 64 + q], wout[(size_t)q * 64 + c], s);
        s *= 0.0625f;
        __bf16 h = (__bf16)s;
        int kp = 4 * (k & 15) + (k >> 4);
        hiT[(size_t)c * 64 + kp] = h;
        loT[(size_t)c * 64 + kp] = (__bf16)(s - (float)h);
    }
    if (tid < 64) {
        float s = 0.0f;
        for (int q = 0; q < 64; ++q)
            s = fmaf(b3[q], wout[(size_t)q * 64 + tid], s);
        b3f[tid] = s * 0.0625f;
    }
}

// ---- counting sort ----
__global__ __launch_bounds__(256) void count_kernel(const int* __restrict__ qidx,
                                                    int* __restrict__ cnt) {
    int e = blockIdx.x * 256 + threadIdx.x;
    if (e < ND) {
        atomicAdd(&cnt[qidx[ND + e]], 1);
        atomicAdd(&cnt[NN + qidx[2 * ND + e]], 1);
    }
}

__global__ __launch_bounds__(256) void scan1(int* data, int* __restrict__ bsum) {
    __shared__ int lds[256];
    const int tid = threadIdx.x;
    const int base = blockIdx.x * SCAN_CHUNK + tid * 8;
    int v[8];
    int tsum = 0;
#pragma unroll
    for (int t = 0; t < 8; ++t) {
        v[t] = (base + t < NCNT) ? data[base + t] : 0;
        tsum += v[t];
    }
    lds[tid] = tsum;
    __syncthreads();
    for (int d = 1; d < 256; d <<= 1) {
        int t = 0;
        if (tid >= d) t = lds[tid - d];
        __syncthreads();
        lds[tid] += t;
        __syncthreads();
    }
    if (tid == 255) bsum[blockIdx.x] = lds[255];
    int run = lds[tid] - tsum;
#pragma unroll
    for (int t = 0; t < 8; ++t) {
        if (base + t < NCNT) data[base + t] = run;
        run += v[t];
    }
}

__global__ __launch_bounds__(128) void scan2(int* __restrict__ bsum) {
    __shared__ int lds[128];
    const int t = threadIdx.x;
    int v = (t < NBLK_SCAN) ? bsum[t] : 0;
    lds[t] = v;
    __syncthreads();
    for (int d = 1; d < 128; d <<= 1) {
        int u = (t >= d) ? lds[t - d] : 0;
        __syncthreads();
        lds[t] += u;
        __syncthreads();
    }
    if (t < NBLK_SCAN) bsum[t] = lds[t] - v;
}

__global__ __launch_bounds__(256) void scan3(int* __restrict__ off,
                                             const int* __restrict__ bsum) {
    const int base = blockIdx.x * SCAN_CHUNK + threadIdx.x * 8;
    const int add = bsum[blockIdx.x];
#pragma unroll
    for (int t = 0; t < 8; ++t) {
        int i = base + t;
        if (i < NCNT) off[i] += add;
    }
}

// fill: per-edge slot in j- and k-sorted order; afterwards off[b] = END of bucket b
__global__ __launch_bounds__(256) void fill_kernel(const int* __restrict__ qidx,
                                                   int* __restrict__ off,
                                                   int* __restrict__ slot_j,
                                                   int* __restrict__ slot_k) {
    int e = blockIdx.x * 256 + threadIdx.x;
    if (e < ND) {
        slot_j[e] = atomicAdd(&off[qidx[ND + e]], 1);
        slot_k[e] = atomicAdd(&off[NN + qidx[2 * ND + e]], 1);
    }
}

// ---- edge MLP: 32 edges/wave, raw-x A-frags split inline, LN stats accumulated
// in-flight during the layer-1 k-loop, LN folded into the f32 epilogue,
// msg written to BOTH sorted slots (128-B-granule scattered stores). ----
__global__ __launch_bounds__(256, 3) void edge_mlp_mfma(
    const float* __restrict__ x, const float* __restrict__ pos,
    const int* __restrict__ qidx, const float* __restrict__ qattr,
    const __bf16* __restrict__ w1h, const __bf16* __restrict__ w1l,
    const float* __restrict__ c1, const float* __restrict__ d1,
    const __bf16* __restrict__ w2h, const __bf16* __restrict__ w2l, const float* __restrict__ b2,
    const __bf16* __restrict__ w3h, const __bf16* __restrict__ w3l, const float* __restrict__ b3f,
    const int* __restrict__ slot_j, const int* __restrict__ slot_k,
    f16* __restrict__ msg)
{
    __shared__ __align__(16) __bf16 hsh[4][2][16 * HS];

    const int tid = threadIdx.x;
    const int w   = tid >> 6;
    const int l   = tid & 63;
    const int m   = l & 15;
    const int kg  = l >> 4;
    const int ebase = (blockIdx.x * 4 + w) * 32;
    if (ebase >= ND) return;               // no barriers: early-out safe

    // A-row indices for both tiles
    int iA[2], lA[2];
#pragma unroll
    for (int t = 0; t < 2; ++t) {
        const int e = ebase + 16 * t + m;
        iA[t] = qidx[e];
        lA[t] = qidx[3 * ND + e];
    }

    // ---- dihedral + raw-extras stats: tile kg on lanes kg<2 ----
    float cosd = 0.f, sind = 0.f, at0 = 0.f, at1 = 0.f, at2 = 0.f, se = 0.f, qe = 0.f;
    if (kg < 2) {
        const int e2 = ebase + 16 * kg + m;
        const int j2 = qidx[ND + e2];
        const int k2 = qidx[2 * ND + e2];
        float3 pi = f3load(pos, iA[kg]), pj = f3load(pos, j2);
        float3 pk = f3load(pos, k2), pl = f3load(pos, lA[kg]);
        float3 d1v_ = f3sub(pj, pi);
        float3 d2v_ = f3sub(pk, pj);
        float3 d3v_ = f3sub(pl, pk);
        float3 n1 = f3cross(d1v_, d2v_);
        float3 n2 = f3cross(d2v_, d3v_);
        float r1 = 1.0f / fmaxf(sqrtf(f3dot(n1, n1)), 1e-6f);
        n1.x *= r1; n1.y *= r1; n1.z *= r1;
        float r2 = 1.0f / fmaxf(sqrtf(f3dot(n2, n2)), 1e-6f);
        n2.x *= r2; n2.y *= r2; n2.z *= r2;
        cosd = fminf(fmaxf(f3dot(n1, n2), -1.0f), 1.0f);
        float rb = 1.0f / fmaxf(sqrtf(f3dot(d2v_, d2v_)), 1e-6f);
        float3 b2n = make_float3(d2v_.x * rb, d2v_.y * rb, d2v_.z * rb);
        float3 mm = f3cross(n1, b2n);
        sind = f3dot(mm, n2);
        at0 = qattr[(size_t)e2 * 3 + 0];
        at1 = qattr[(size_t)e2 * 3 + 1];
        at2 = qattr[(size_t)e2 * 3 + 2];
        se = at0 + at1 + at2 + cosd + sind;                      // raw extras sum
        qe = at0 * at0 + at1 * at1 + at2 * at2 + cosd * cosd + sind * sind;
    }

    // raw extras A-frags (gamma lives ONLY in w1g; A side stays raw)
    bf16x8 ah4[2], al4[2];
#pragma unroll
    for (int t = 0; t < 2; ++t) {
        const int src = m + 16 * t;
        float u4[8] = {__shfl(at0, src), __shfl(at1, src), __shfl(at2, src),
                       __shfl(cosd, src), __shfl(sind, src), 0.f, 0.f, 0.f};
        float g0 = (kg == 0) ? 1.0f : 0.0f;
#pragma unroll
        for (int j = 0; j < 8; ++j) {
            float v = u4[j] * g0;
            __bf16 h = (__bf16)v;
            ah4[t][j] = h;
            al4[t][j] = (__bf16)(v - (float)h);
        }
    }

    // ---- layer 1: P = raw_x @ w1g (+ extras), split 3-MFMA, stats in-flight ----
    f32x4 acc[2][4];
#pragma unroll
    for (int t = 0; t < 2; ++t)
#pragma unroll
        for (int nt = 0; nt < 4; ++nt) acc[t][nt] = (f32x4){0.f, 0.f, 0.f, 0.f};

    // extras slice first (retires ah4/al4 early)
#pragma unroll
    for (int nt = 0; nt < 4; ++nt) {
        const size_t wb = (size_t)(16 * nt + m) * K1P + 128 + 8 * kg;
        bf16x8 bh = *(const bf16x8*)(w1h + wb);
        bf16x8 bl = *(const bf16x8*)(w1l + wb);
        acc[0][nt] = mfma_bf16(ah4[0], bh, acc[0][nt]);
        acc[0][nt] = mfma_bf16(al4[0], bh, acc[0][nt]);
        acc[0][nt] = mfma_bf16(ah4[0], bl, acc[0][nt]);
        acc[1][nt] = mfma_bf16(ah4[1], bh, acc[1][nt]);
        acc[1][nt] = mfma_bf16(al4[1], bh, acc[1][nt]);
        acc[1][nt] = mfma_bf16(ah4[1], bl, acc[1][nt]);
    }

    float st1[2] = {0.f, 0.f}, st2[2] = {0.f, 0.f};
#pragma unroll
    for (int s = 0; s < 4; ++s) {
        const int r0 = (s < 2) ? iA[0] : lA[0];
        const int r1 = (s < 2) ? iA[1] : lA[1];
        const int colo = 32 * (s & 1) + 8 * kg;
        float vv0[8], vv1[8];
        *(float4*)&vv0[0] = *(const float4*)(x + (size_t)r0 * 64 + colo);
        *(float4*)&vv0[4] = *(const float4*)(x + (size_t)r0 * 64 + colo + 4);
        *(float4*)&vv1[0] = *(const float4*)(x + (size_t)r1 * 64 + colo);
        *(float4*)&vv1[4] = *(const float4*)(x + (size_t)r1 * 64 + colo + 4);
        bf16x8 a0h, a0l, a1h, a1l;
#pragma unroll
        for (int j = 0; j < 8; ++j) {
            float v0 = vv0[j], v1 = vv1[j];
            __bf16 h0 = (__bf16)v0, h1 = (__bf16)v1;
            a0h[j] = h0; a0l[j] = (__bf16)(v0 - (float)h0);
            a1h[j] = h1; a1l[j] = (__bf16)(v1 - (float)h1);
            st1[0] += v0; st2[0] = fmaf(v0, v0, st2[0]);
            st1[1] += v1; st2[1] = fmaf(v1, v1, st2[1]);
        }
#pragma unroll
        for (int nt = 0; nt < 4; ++nt) {
            const size_t wb = (size_t)(16 * nt + m) * K1P + 32 * s + 8 * kg;
            bf16x8 bh = *(const bf16x8*)(w1h + wb);
            bf16x8 bl = *(const bf16x8*)(w1l + wb);
            acc[0][nt] = mfma_bf16(a0h, bh, acc[0][nt]);
            acc[0][nt] = mfma_bf16(a0l, bh, acc[0][nt]);
            acc[0][nt] = mfma_bf16(a0h, bl, acc[0][nt]);
            acc[1][nt] = mfma_bf16(a1h, bh, acc[1][nt]);
            acc[1][nt] = mfma_bf16(a1l, bh, acc[1][nt]);
            acc[1][nt] = mfma_bf16(a1h, bl, acc[1][nt]);
        }
    }

    // ---- LN stats: butterfly x-part over the 4 k-group lanes, add extras ----
    float rs_[2], mn_[2];
#pragma unroll
    for (int t = 0; t < 2; ++t) {
        float s1 = st1[t], s2 = st2[t];
        s1 += __shfl_xor(s1, 16); s1 += __shfl_xor(s1, 32);
        s2 += __shfl_xor(s2, 16); s2 += __shfl_xor(s2, 32);
        const int src = m + 16 * t;
        float S = s1 + __shfl(se, src);
        float Q = s2 + __shfl(qe, src);
        float mu  = S * (1.0f / INDIM);
        float var = Q * (1.0f / INDIM) - mu * mu;
        float rsv = rsqrtf(fmaxf(var, 0.0f) + 1e-5f);
        rs_[t] = rsv;
        mn_[t] = -mu * rsv;
    }

    // epilogue 1: h1 = silu(rs*P + (-rs*mu)*c1 + d1), permuted-col 8B LDS stores
    float c1v[4], d1v[4], b2v[4], b3v[4];
#pragma unroll
    for (int nt = 0; nt < 4; ++nt) {
        c1v[nt] = c1[16 * nt + m];
        d1v[nt] = d1[16 * nt + m];
        b2v[nt] = b2[16 * nt + m];
        b3v[nt] = b3f[16 * nt + m];
    }
#pragma unroll
    for (int t = 0; t < 2; ++t) {
        __bf16* hhw = &hsh[w][t][0];
#pragma unroll
        for (int r = 0; r < 4; ++r) {
            float rse = __shfl(rs_[t], 4 * kg + r);
            float mne = __shfl(mn_[t], 4 * kg + r);
            bf16x4 hv4;
#pragma unroll
            for (int nt = 0; nt < 4; ++nt)
                hv4[nt] = (__bf16)fsilu(fmaf(rse, acc[t][nt][r],
                                        fmaf(mne, c1v[nt], d1v[nt])));
            *(bf16x4*)(hhw + (4 * kg + r) * HS + m * 4) = hv4;
        }
    }

    // ---- layer 2: hi-A x split-W ----
    bf16x8 a2h[2][2];
#pragma unroll
    for (int t = 0; t < 2; ++t)
#pragma unroll
        for (int s = 0; s < 2; ++s)
            a2h[t][s] = *(const bf16x8*)(&hsh[w][t][m * HS + 32 * s + 8 * kg]);
    f32x4 acc2[2][4];
#pragma unroll
    for (int t = 0; t < 2; ++t)
#pragma unroll
        for (int nt = 0; nt < 4; ++nt) acc2[t][nt] = (f32x4){0.f, 0.f, 0.f, 0.f};
#pragma unroll
    for (int s = 0; s < 2; ++s) {
#pragma unroll
        for (int nt = 0; nt < 4; ++nt) {
            const size_t wb = (size_t)(16 * nt + m) * 64 + 32 * s + 8 * kg;
            bf16x8 bh = *(const bf16x8*)(w2h + wb);
            bf16x8 bl = *(const bf16x8*)(w2l + wb);
            acc2[0][nt] = mfma_bf16(a2h[0][s], bh, acc2[0][nt]);
            acc2[0][nt] = mfma_bf16(a2h[0][s], bl, acc2[0][nt]);
            acc2[1][nt] = mfma_bf16(a2h[1][s], bh, acc2[1][nt]);
            acc2[1][nt] = mfma_bf16(a2h[1][s], bl, acc2[1][nt]);
        }
    }
#pragma unroll
    for (int t = 0; t < 2; ++t) {
        __bf16* hhw = &hsh[w][t][0];
#pragma unroll
        for (int r = 0; r < 4; ++r) {
            bf16x4 hv4;
#pragma unroll
            for (int nt = 0; nt < 4; ++nt)
                hv4[nt] = (__bf16)fsilu(acc2[t][nt][r] + b2v[nt]);
            *(bf16x4*)(hhw + (4 * kg + r) * HS + m * 4) = hv4;
        }
    }

    // ---- layer 3 (w_out + scale folded) ----
    bf16x8 a3h[2][2];
#pragma unroll
    for (int t = 0; t < 2; ++t)
#pragma unroll
        for (int s = 0; s < 2; ++s)
            a3h[t][s] = *(const bf16x8*)(&hsh[w][t][m * HS + 32 * s + 8 * kg]);
    f32x4 acc3[2][4];
#pragma unroll
    for (int t = 0; t < 2; ++t)
#pragma unroll
        for (int nt = 0; nt < 4; ++nt) acc3[t][nt] = (f32x4){0.f, 0.f, 0.f, 0.f};
#pragma unroll
    for (int s = 0; s < 2; ++s) {
#pragma unroll
        for (int nt = 0; nt < 4; ++nt) {
            const size_t wb = (size_t)(16 * nt + m) * 64 + 32 * s + 8 * kg;
            bf16x8 bh = *(const bf16x8*)(w3h + wb);
            bf16x8 bl = *(const bf16x8*)(w3l + wb);
            acc3[0][nt] = mfma_bf16(a3h[0][s], bh, acc3[0][nt]);
            acc3[0][nt] = mfma_bf16(a3h[0][s], bl, acc3[0][nt]);
            acc3[1][nt] = mfma_bf16(a3h[1][s], bh, acc3[1][nt]);
            acc3[1][nt] = mfma_bf16(a3h[1][s], bl, acc3[1][nt]);
        }
    }

    // ---- msg: f16x4 stores to BOTH sorted slots (16 lanes/row -> 128-B granules) ----
#pragma unroll
    for (int t = 0; t < 2; ++t) {
#pragma unroll
        for (int r = 0; r < 4; ++r) {
            f16x4 v;
#pragma unroll
            for (int nt = 0; nt < 4; ++nt)
                v[nt] = (f16)(acc3[t][nt][r] + b3v[nt]);
            const int er = ebase + 16 * t + 4 * kg + r;
            *(f16x4*)(msg + (size_t)slot_j[er] * 64 + m * 4) = v;
            *(f16x4*)(msg + (size_t)slot_k[er] * 64 + m * 4) = v;
        }
    }
}

// ---- node aggregation: sequential sorted-slot reads, shfl reduce, permuted cols ----
__global__ __launch_bounds__(256) void node_out(const f16* __restrict__ msg,
                                                const int* __restrict__ off,
                                                float* __restrict__ out) {
    const int w   = threadIdx.x >> 6;
    const int l   = threadIdx.x & 63;
    const int sub = l >> 4;      // row-within-4-chunk
    const int m16 = l & 15;      // permuted col group: cols' 4*m16..+3
    for (int n = blockIdx.x * 4 + w; n < NN; n += gridDim.x * 4) {
        int ja = (n == 0) ? 0 : off[n - 1];
        int jb = off[n];
        int ka = off[NN + n - 1];   // n==0 -> off[NN-1] = start of k-region
        int kb = off[NN + n];
        float s0 = 0.f, s1 = 0.f, s2 = 0.f, s3 = 0.f;
        float t0 = 0.f, t1 = 0.f, t2 = 0.f, t3 = 0.f;
        for (int p = ja + sub; p < jb; p += 4) {
            f16x4 v = *(const f16x4*)(msg + (size_t)p * 64 + m16 * 4);
            s0 += (float)v[0]; s1 += (float)v[1];
            s2 += (float)v[2]; s3 += (float)v[3];
        }
        for (int p = ka + sub; p < kb; p += 4) {
            f16x4 v = *(const f16x4*)(msg + (size_t)p * 64 + m16 * 4);
            t0 += (float)v[0]; t1 += (float)v[1];
            t2 += (float)v[2]; t3 += (float)v[3];
        }
        s0 += __shfl_xor(s0, 16); s0 += __shfl_xor(s0, 32);
        s1 += __shfl_xor(s1, 16); s1 += __shfl_xor(s1, 32);
        s2 += __shfl_xor(s2, 16); s2 += __shfl_xor(s2, 32);
        s3 += __shfl_xor(s3, 16); s3 += __shfl_xor(s3, 32);
        t0 += __shfl_xor(t0, 16); t0 += __shfl_xor(t0, 32);
        t1 += __shfl_xor(t1, 16); t1 += __shfl_xor(t1, 32);
        t2 += __shfl_xor(t2, 16); t2 += __shfl_xor(t2, 32);
        t3 += __shfl_xor(t3, 16); t3 += __shfl_xor(t3, 32);
        if (sub == 0) {
            float rj = 1.0f / fmaxf((float)(jb - ja), 1.0f);
            float rk = 1.0f / fmaxf((float)(kb - ka), 1.0f);
            float* o = out + (size_t)n * 64;
            o[m16]      = s0 * rj + t0 * rk;   // col' 4m+nt <-> true col 16nt+m
            o[16 + m16] = s1 * rj + t1 * rk;
            o[32 + m16] = s2 * rj + t2 * rk;
            o[48 + m16] = s3 * rj + t3 * rk;
        }
    }
}

// ============================ launch ============================

extern "C" void kernel_launch(void* const* d_in, const int* in_sizes, int n_in,
                              void* d_out, int out_size, void* d_ws, size_t ws_size,
                              hipStream_t stream) {
    (void)in_sizes; (void)n_in; (void)out_size;

    const float* x     = (const float*)d_in[0];
    const float* pos   = (const float*)d_in[1];
    const int*   qidx  = (const int*)d_in[2];
    const float* qattr = (const float*)d_in[3];
    const float* gamma = (const float*)d_in[4];
    const float* beta  = (const float*)d_in[5];
    const float* w1    = (const float*)d_in[6];
    const float* b1    = (const float*)d_in[7];
    const float* w2    = (const float*)d_in[8];
    const float* b2    = (const float*)d_in[9];
    const float* w3    = (const float*)d_in[10];
    const float* b3    = (const float*)d_in[11];
    const float* w_out = (const float*)d_in[12];
    float* out = (float*)d_out;

    size_t o = 0;
    auto alloc = [&](size_t bytes) { size_t r = o; o = (o + bytes + 255) & ~(size_t)255; return r; };
    char* W = (char*)d_ws;
    f16*    msg    = (f16*)   (W + alloc((size_t)2 * ND * 64 * sizeof(f16)));   // 256 MB
    int*    slot_j = (int*)   (W + alloc((size_t)ND * sizeof(int)));
    int*    slot_k = (int*)   (W + alloc((size_t)ND * sizeof(int)));
    int*    off    = (int*)   (W + alloc((size_t)NCNT * sizeof(int)));
    int*    bsum   = (int*)   (W + alloc((size_t)NBLK_SCAN * sizeof(int)));
    __bf16* w1h    = (__bf16*)(W + alloc((size_t)64 * K1P * sizeof(__bf16)));
    __bf16* w1l    = (__bf16*)(W + alloc((size_t)64 * K1P * sizeof(__bf16)));
    __bf16* w2h    = (__bf16*)(W + alloc((size_t)64 * 64 * sizeof(__bf16)));
    __bf16* w2l    = (__bf16*)(W + alloc((size_t)64 * 64 * sizeof(__bf16)));
    __bf16* w3h    = (__bf16*)(W + alloc((size_t)64 * 64 * sizeof(__bf16)));
    __bf16* w3l    = (__bf16*)(W + alloc((size_t)64 * 64 * sizeof(__bf16)));
    float*  c1     = (float*) (W + alloc((size_t)64 * sizeof(float)));
    float*  d1     = (float*) (W + alloc((size_t)64 * sizeof(float)));
    float*  b3f    = (float*) (W + alloc((size_t)64 * sizeof(float)));
    if (ws_size < o) return;   // ~264.9 MB, same footprint class as rounds 3-5 (fit)

    // weight prep
    prep_w1g<<<(64 * K1P + 255) / 256, 256, 0, stream>>>(w1, gamma, w1h, w1l);
    prep_lin<<<1, 64, 0, stream>>>(w1, b1, gamma, beta, c1, d1);
    prep_w<<<16, 256, 0, stream>>>(w2, w2h, w2l);
    prep_w3<<<1, 256, 0, stream>>>(w3, b3, w_out, w3h, w3l, b3f);

    // counting sort
    hipMemsetAsync(off, 0, (size_t)NCNT * sizeof(int), stream);
    count_kernel<<<(ND + 255) / 256, 256, 0, stream>>>(qidx, off);
    scan1<<<NBLK_SCAN, 256, 0, stream>>>(off, bsum);
    scan2<<<1, 128, 0, stream>>>(bsum);
    scan3<<<NBLK_SCAN, 256, 0, stream>>>(off, bsum);
    fill_kernel<<<(ND + 255) / 256, 256, 0, stream>>>(qidx, off, slot_j, slot_k);

    // edge MLP -> msg (dual sorted-slot scatter)
    edge_mlp_mfma<<<(ND + 127) / 128, 256, 0, stream>>>(x, pos, qidx, qattr,
                                                        w1h, w1l, c1, d1,
                                                        w2h, w2l, b2, w3h, w3l, b3f,
                                                        slot_j, slot_k, msg);
    // node aggregation (sequential segmented mean)
    node_out<<<4096, 256, 0, stream>>>(msg, off, out);
}

// Round 8
// 541.395 us; speedup vs baseline: 1.2259x; 1.1007x over previous
//
#include <hip/hip_runtime.h>
#include <math.h>

#define NN 100000
#define ND 1000000
#define INDIM 133
#define K1P 160                 // padded input dim (5 x 32)
#define NCNT (2*NN)
#define SCAN_CHUNK 2048
#define NBLK_SCAN ((NCNT + SCAN_CHUNK - 1) / SCAN_CHUNK)
#define HS 72                   // LDS h-tile row stride in bf16 elems (144B)

typedef __bf16 bf16x8 __attribute__((ext_vector_type(8)));
typedef __bf16 bf16x4 __attribute__((ext_vector_type(4)));
typedef float  f32x4  __attribute__((ext_vector_type(4)));
typedef _Float16 f16;
typedef _Float16 f16x4 __attribute__((ext_vector_type(4)));

__device__ __forceinline__ f32x4 mfma_bf16(bf16x8 a, bf16x8 b, f32x4 c) {
    return __builtin_amdgcn_mfma_f32_16x16x32_bf16(a, b, c, 0, 0, 0);
}

__device__ __forceinline__ float3 f3sub(float3 a, float3 b) {
    return make_float3(a.x - b.x, a.y - b.y, a.z - b.z);
}
__device__ __forceinline__ float3 f3cross(float3 a, float3 b) {
    return make_float3(a.y * b.z - a.z * b.y, a.z * b.x - a.x * b.z, a.x * b.y - a.y * b.x);
}
__device__ __forceinline__ float f3dot(float3 a, float3 b) {
    return a.x * b.x + a.y * b.y + a.z * b.z;
}
__device__ __forceinline__ float3 f3load(const float* __restrict__ p, int idx) {
    const float* q = p + (size_t)idx * 3;
    return make_float3(q[0], q[1], q[2]);
}
__device__ __forceinline__ float fsilu(float v) {
    return v / (1.0f + __expf(-v));
}

// ---- per-node LN partial stats: sq[n] = (sum x[n,:], sum x[n,:]^2) ----
__global__ __launch_bounds__(256) void prep_sq(const float* __restrict__ x,
                                               float2* __restrict__ sq) {
    const int n = blockIdx.x * 4 + (threadIdx.x >> 6);
    const int c = threadIdx.x & 63;
    float v = x[(size_t)n * 64 + c];
    float s = v, q = v * v;
#pragma unroll
    for (int d = 1; d < 64; d <<= 1) {
        s += __shfl_xor(s, d);
        q += __shfl_xor(q, d);
    }
    if (c == 0) sq[n] = make_float2(s, q);
}

// ---- all weight prep in one kernel, dispatched by blockIdx ----
// blocks 0..39: w1g split (64*160); block 40: c1/d1; blocks 41..56: w2 permuted;
// block 57: w3 fold (w_out + 2^-4) permuted.
__global__ __launch_bounds__(256) void prep_all(
    const float* __restrict__ w1, const float* __restrict__ b1,
    const float* __restrict__ w2,
    const float* __restrict__ w3, const float* __restrict__ b3,
    const float* __restrict__ wout,
    const float* __restrict__ gamma, const float* __restrict__ beta,
    __bf16* __restrict__ w1h, __bf16* __restrict__ w1l,
    float* __restrict__ c1, float* __restrict__ d1,
    __bf16* __restrict__ w2h, __bf16* __restrict__ w2l,
    __bf16* __restrict__ w3h, __bf16* __restrict__ w3l,
    float* __restrict__ b3f)
{
    const int b = blockIdx.x, tid = threadIdx.x;
    if (b < 40) {                       // w1g = diag(gamma) @ w1, [n][k] padded, hi/lo
        int idx = b * 256 + tid;        // 40*256 = 10240 = 64*160 exactly
        int n = idx / K1P, kp = idx - n * K1P;
        float v = (kp < INDIM) ? gamma[kp] * w1[(size_t)kp * 64 + n] : 0.0f;
        __bf16 h = (__bf16)v;
        w1h[idx] = h;
        w1l[idx] = (__bf16)(v - (float)h);
    } else if (b == 40) {               // c1 = gamma@w1, d1 = beta@w1 + b1
        if (tid < 64) {
            float sc = 0.0f, sd = 0.0f;
            for (int k = 0; k < INDIM; ++k) {
                float wv = w1[(size_t)k * 64 + tid];
                sc = fmaf(gamma[k], wv, sc);
                sd = fmaf(beta[k], wv, sd);
            }
            c1[tid] = sc;
            d1[tid] = sd + b1[tid];
        }
    } else if (b < 57) {                // w2 transposed [n][k'], permuted k
        int idx = (b - 41) * 256 + tid; // 16*256 = 4096
        int n = idx >> 6, kp = idx & 63;
        int ko = 16 * (kp & 3) + (kp >> 2);
        float v = w2[(size_t)ko * 64 + n];
        __bf16 h = (__bf16)v;
        w2h[idx] = h;
        w2l[idx] = (__bf16)(v - (float)h);
    } else {                            // w3'' = (w3 @ wout) * 2^-4, [c][k'] permuted
        for (int idx = tid; idx < 64 * 64; idx += 256) {
            int k = idx >> 6, c = idx & 63;
            float s = 0.0f;
            for (int q = 0; q < 64; ++q)
                s = fmaf(w3[(size_t)k * 64 + q], wout[(size_t)q * 64 + c], s);
            s *= 0.0625f;
            __bf16 h = (__bf16)s;
            int kp = 4 * (k & 15) + (k >> 4);
            w3h[(size_t)c * 64 + kp] = h;
            w3l[(size_t)c * 64 + kp] = (__bf16)(s - (float)h);
        }
        if (tid < 64) {
            float s = 0.0f;
            for (int q = 0; q < 64; ++q)
                s = fmaf(b3[q], wout[(size_t)q * 64 + tid], s);
            b3f[tid] = s * 0.0625f;
        }
    }
}

// ---- counting sort ----
__global__ __launch_bounds__(256) void count_kernel(const int* __restrict__ qidx,
                                                    int* __restrict__ cnt) {
    int e = blockIdx.x * 256 + threadIdx.x;
    if (e < ND) {
        atomicAdd(&cnt[qidx[ND + e]], 1);
        atomicAdd(&cnt[NN + qidx[2 * ND + e]], 1);
    }
}

__global__ __launch_bounds__(256) void scan1(int* data, int* __restrict__ bsum) {
    __shared__ int lds[256];
    const int tid = threadIdx.x;
    const int base = blockIdx.x * SCAN_CHUNK + tid * 8;
    int v[8];
    int tsum = 0;
#pragma unroll
    for (int t = 0; t < 8; ++t) {
        v[t] = (base + t < NCNT) ? data[base + t] : 0;
        tsum += v[t];
    }
    lds[tid] = tsum;
    __syncthreads();
    for (int d = 1; d < 256; d <<= 1) {
        int t = 0;
        if (tid >= d) t = lds[tid - d];
        __syncthreads();
        lds[tid] += t;
        __syncthreads();
    }
    if (tid == 255) bsum[blockIdx.x] = lds[255];
    int run = lds[tid] - tsum;
#pragma unroll
    for (int t = 0; t < 8; ++t) {
        if (base + t < NCNT) data[base + t] = run;
        run += v[t];
    }
}

__global__ __launch_bounds__(128) void scan2(int* __restrict__ bsum) {
    __shared__ int lds[128];
    const int t = threadIdx.x;
    int v = (t < NBLK_SCAN) ? bsum[t] : 0;
    lds[t] = v;
    __syncthreads();
    for (int d = 1; d < 128; d <<= 1) {
        int u = (t >= d) ? lds[t - d] : 0;
        __syncthreads();
        lds[t] += u;
        __syncthreads();
    }
    if (t < NBLK_SCAN) bsum[t] = lds[t] - v;
}

__global__ __launch_bounds__(256) void scan3(int* __restrict__ off,
                                             const int* __restrict__ bsum) {
    const int base = blockIdx.x * SCAN_CHUNK + threadIdx.x * 8;
    const int add = bsum[blockIdx.x];
#pragma unroll
    for (int t = 0; t < 8; ++t) {
        int i = base + t;
        if (i < NCNT) off[i] += add;
    }
}

// fill: per-edge slot in j- and k-sorted order; afterwards off[b] = END of bucket b
__global__ __launch_bounds__(256) void fill_kernel(const int* __restrict__ qidx,
                                                   int* __restrict__ off,
                                                   int* __restrict__ slot_j,
                                                   int* __restrict__ slot_k) {
    int e = blockIdx.x * 256 + threadIdx.x;
    if (e < ND) {
        slot_j[e] = atomicAdd(&off[qidx[ND + e]], 1);
        slot_k[e] = atomicAdd(&off[NN + qidx[2 * ND + e]], 1);
    }
}

// ---- edge MLP: 64 edges/wave (4 M-tiles sharing every B-fragment load),
// dihedral on ALL 64 lanes (lane's kg = its tile), LN stats from sq table,
// LN folded into f32 epilogue, dual sorted-slot msg scatter. ----
__global__ __launch_bounds__(256, 3) void edge_mlp_mfma(
    const float* __restrict__ x, const float2* __restrict__ sq,
    const float* __restrict__ pos,
    const int* __restrict__ qidx, const float* __restrict__ qattr,
    const __bf16* __restrict__ w1h, const __bf16* __restrict__ w1l,
    const float* __restrict__ c1, const float* __restrict__ d1,
    const __bf16* __restrict__ w2h, const __bf16* __restrict__ w2l, const float* __restrict__ b2,
    const __bf16* __restrict__ w3h, const __bf16* __restrict__ w3l, const float* __restrict__ b3f,
    const int* __restrict__ slot_j, const int* __restrict__ slot_k,
    f16* __restrict__ msg)
{
    __shared__ __align__(16) __bf16 hsh[4][4][16 * HS];   // 36 KB

    const int tid = threadIdx.x;
    const int w   = tid >> 6;
    const int l   = tid & 63;
    const int m   = l & 15;
    const int kg  = l >> 4;
    const int ebase = (blockIdx.x * 4 + w) * 64;
    if (ebase >= ND) return;               // no barriers: early-out safe

    // A-row indices for all 4 tiles
    int iA[4], lA[4];
#pragma unroll
    for (int t = 0; t < 4; ++t) {
        const int e = ebase + 16 * t + m;
        iA[t] = qidx[e];
        lA[t] = qidx[3 * ND + e];
    }

    // ---- dihedral + raw-extras: lane handles tile kg, edge m (all 64 lanes busy) ----
    float cosd, sind, at0, at1, at2, se, qe;
    {
        const int e2 = ebase + 16 * kg + m;
        const int i2 = qidx[e2];
        const int j2 = qidx[ND + e2];
        const int k2 = qidx[2 * ND + e2];
        const int l2 = qidx[3 * ND + e2];
        float3 pi = f3load(pos, i2), pj = f3load(pos, j2);
        float3 pk = f3load(pos, k2), pl = f3load(pos, l2);
        float3 d1v_ = f3sub(pj, pi);
        float3 d2v_ = f3sub(pk, pj);
        float3 d3v_ = f3sub(pl, pk);
        float3 n1 = f3cross(d1v_, d2v_);
        float3 n2 = f3cross(d2v_, d3v_);
        float r1 = 1.0f / fmaxf(sqrtf(f3dot(n1, n1)), 1e-6f);
        n1.x *= r1; n1.y *= r1; n1.z *= r1;
        float r2 = 1.0f / fmaxf(sqrtf(f3dot(n2, n2)), 1e-6f);
        n2.x *= r2; n2.y *= r2; n2.z *= r2;
        cosd = fminf(fmaxf(f3dot(n1, n2), -1.0f), 1.0f);
        float rb = 1.0f / fmaxf(sqrtf(f3dot(d2v_, d2v_)), 1e-6f);
        float3 b2n = make_float3(d2v_.x * rb, d2v_.y * rb, d2v_.z * rb);
        float3 mm = f3cross(n1, b2n);
        sind = f3dot(mm, n2);
        at0 = qattr[(size_t)e2 * 3 + 0];
        at1 = qattr[(size_t)e2 * 3 + 1];
        at2 = qattr[(size_t)e2 * 3 + 2];
        se = at0 + at1 + at2 + cosd + sind;
        qe = at0 * at0 + at1 * at1 + at2 * at2 + cosd * cosd + sind * sind;
    }

    // raw extras A-frags + LN stats per tile (sq table + shuffled extras)
    bf16x8 ah4[4], al4[4];
    float rs_[4], mn_[4];
#pragma unroll
    for (int t = 0; t < 4; ++t) {
        const int src = m + 16 * t;
        float u4[8] = {__shfl(at0, src), __shfl(at1, src), __shfl(at2, src),
                       __shfl(cosd, src), __shfl(sind, src), 0.f, 0.f, 0.f};
        float g0 = (kg == 0) ? 1.0f : 0.0f;
#pragma unroll
        for (int j = 0; j < 8; ++j) {
            float v = u4[j] * g0;
            __bf16 h = (__bf16)v;
            ah4[t][j] = h;
            al4[t][j] = (__bf16)(v - (float)h);
        }
        float2 si = sq[iA[t]], sl = sq[lA[t]];
        float S = si.x + sl.x + __shfl(se, src);
        float Q = si.y + sl.y + __shfl(qe, src);
        float mu  = S * (1.0f / INDIM);
        float var = Q * (1.0f / INDIM) - mu * mu;
        float rsv = rsqrtf(fmaxf(var, 0.0f) + 1e-5f);
        rs_[t] = rsv;
        mn_[t] = -mu * rsv;
    }

    // ---- layer 1: P = raw_x @ w1g (+ extras), split 3-MFMA ----
    f32x4 acc[4][4];
#pragma unroll
    for (int t = 0; t < 4; ++t)
#pragma unroll
        for (int nt = 0; nt < 4; ++nt) acc[t][nt] = (f32x4){0.f, 0.f, 0.f, 0.f};

    // extras slice first (retires ah4/al4 early)
#pragma unroll
    for (int nt = 0; nt < 4; ++nt) {
        const size_t wb = (size_t)(16 * nt + m) * K1P + 128 + 8 * kg;
        bf16x8 bh = *(const bf16x8*)(w1h + wb);
        bf16x8 bl = *(const bf16x8*)(w1l + wb);
#pragma unroll
        for (int t = 0; t < 4; ++t) {
            acc[t][nt] = mfma_bf16(ah4[t], bh, acc[t][nt]);
            acc[t][nt] = mfma_bf16(al4[t], bh, acc[t][nt]);
            acc[t][nt] = mfma_bf16(ah4[t], bl, acc[t][nt]);
        }
    }

#pragma unroll
    for (int s = 0; s < 4; ++s) {
        const int colo = 32 * (s & 1) + 8 * kg;
        bf16x8 ath[4], atl[4];
#pragma unroll
        for (int t = 0; t < 4; ++t) {
            const int r_ = (s < 2) ? iA[t] : lA[t];
            float vv[8];
            *(float4*)&vv[0] = *(const float4*)(x + (size_t)r_ * 64 + colo);
            *(float4*)&vv[4] = *(const float4*)(x + (size_t)r_ * 64 + colo + 4);
#pragma unroll
            for (int j = 0; j < 8; ++j) {
                float v = vv[j];
                __bf16 h = (__bf16)v;
                ath[t][j] = h;
                atl[t][j] = (__bf16)(v - (float)h);
            }
        }
#pragma unroll
        for (int nt = 0; nt < 4; ++nt) {
            const size_t wb = (size_t)(16 * nt + m) * K1P + 32 * s + 8 * kg;
            bf16x8 bh = *(const bf16x8*)(w1h + wb);
            bf16x8 bl = *(const bf16x8*)(w1l + wb);
#pragma unroll
            for (int t = 0; t < 4; ++t) {
                acc[t][nt] = mfma_bf16(ath[t], bh, acc[t][nt]);
                acc[t][nt] = mfma_bf16(atl[t], bh, acc[t][nt]);
                acc[t][nt] = mfma_bf16(ath[t], bl, acc[t][nt]);
            }
        }
    }

    // epilogue 1: h1 = silu(rs*P + (-rs*mu)*c1 + d1), permuted-col 8B LDS stores
    float c1v[4], d1v[4], b2v[4], b3v[4];
#pragma unroll
    for (int nt = 0; nt < 4; ++nt) {
        c1v[nt] = c1[16 * nt + m];
        d1v[nt] = d1[16 * nt + m];
        b2v[nt] = b2[16 * nt + m];
        b3v[nt] = b3f[16 * nt + m];
    }
#pragma unroll
    for (int t = 0; t < 4; ++t) {
        __bf16* hhw = &hsh[w][t][0];
#pragma unroll
        for (int r = 0; r < 4; ++r) {
            float rse = __shfl(rs_[t], 4 * kg + r);
            float mne = __shfl(mn_[t], 4 * kg + r);
            bf16x4 hv4;
#pragma unroll
            for (int nt = 0; nt < 4; ++nt)
                hv4[nt] = (__bf16)fsilu(fmaf(rse, acc[t][nt][r],
                                        fmaf(mne, c1v[nt], d1v[nt])));
            *(bf16x4*)(hhw + (4 * kg + r) * HS + m * 4) = hv4;
        }
    }

    // ---- layer 2: hi-A x split-W ----
    bf16x8 a2h[4][2];
#pragma unroll
    for (int t = 0; t < 4; ++t)
#pragma unroll
        for (int s = 0; s < 2; ++s)
            a2h[t][s] = *(const bf16x8*)(&hsh[w][t][m * HS + 32 * s + 8 * kg]);
    f32x4 acc2[4][4];
#pragma unroll
    for (int t = 0; t < 4; ++t)
#pragma unroll
        for (int nt = 0; nt < 4; ++nt) acc2[t][nt] = (f32x4){0.f, 0.f, 0.f, 0.f};
#pragma unroll
    for (int s = 0; s < 2; ++s) {
#pragma unroll
        for (int nt = 0; nt < 4; ++nt) {
            const size_t wb = (size_t)(16 * nt + m) * 64 + 32 * s + 8 * kg;
            bf16x8 bh = *(const bf16x8*)(w2h + wb);
            bf16x8 bl = *(const bf16x8*)(w2l + wb);
#pragma unroll
            for (int t = 0; t < 4; ++t) {
                acc2[t][nt] = mfma_bf16(a2h[t][s], bh, acc2[t][nt]);
                acc2[t][nt] = mfma_bf16(a2h[t][s], bl, acc2[t][nt]);
            }
        }
    }
#pragma unroll
    for (int t = 0; t < 4; ++t) {
        __bf16* hhw = &hsh[w][t][0];
#pragma unroll
        for (int r = 0; r < 4; ++r) {
            bf16x4 hv4;
#pragma unroll
            for (int nt = 0; nt < 4; ++nt)
                hv4[nt] = (__bf16)fsilu(acc2[t][nt][r] + b2v[nt]);
            *(bf16x4*)(hhw + (4 * kg + r) * HS + m * 4) = hv4;
        }
    }

    // ---- layer 3 (w_out + scale folded) ----
    bf16x8 a3h[4][2];
#pragma unroll
    for (int t = 0; t < 4; ++t)
#pragma unroll
        for (int s = 0; s < 2; ++s)
            a3h[t][s] = *(const bf16x8*)(&hsh[w][t][m * HS + 32 * s + 8 * kg]);
    f32x4 acc3[4][4];
#pragma unroll
    for (int t = 0; t < 4; ++t)
#pragma unroll
        for (int nt = 0; nt < 4; ++nt) acc3[t][nt] = (f32x4){0.f, 0.f, 0.f, 0.f};
#pragma unroll
    for (int s = 0; s < 2; ++s) {
#pragma unroll
        for (int nt = 0; nt < 4; ++nt) {
            const size_t wb = (size_t)(16 * nt + m) * 64 + 32 * s + 8 * kg;
            bf16x8 bh = *(const bf16x8*)(w3h + wb);
            bf16x8 bl = *(const bf16x8*)(w3l + wb);
#pragma unroll
            for (int t = 0; t < 4; ++t) {
                acc3[t][nt] = mfma_bf16(a3h[t][s], bh, acc3[t][nt]);
                acc3[t][nt] = mfma_bf16(a3h[t][s], bl, acc3[t][nt]);
            }
        }
    }

    // ---- msg: f16x4 stores to BOTH sorted slots (16 lanes/row -> 128-B granules) ----
#pragma unroll
    for (int t = 0; t < 4; ++t) {
#pragma unroll
        for (int r = 0; r < 4; ++r) {
            f16x4 v;
#pragma unroll
            for (int nt = 0; nt < 4; ++nt)
                v[nt] = (f16)(acc3[t][nt][r] + b3v[nt]);
            const int er = ebase + 16 * t + 4 * kg + r;
            *(f16x4*)(msg + (size_t)slot_j[er] * 64 + m * 4) = v;
            *(f16x4*)(msg + (size_t)slot_k[er] * 64 + m * 4) = v;
        }
    }
}

// ---- node aggregation: sequential sorted-slot reads, shfl reduce, permuted cols ----
__global__ __launch_bounds__(256) void node_out(const f16* __restrict__ msg,
                                                const int* __restrict__ off,
                                                float* __restrict__ out) {
    const int w   = threadIdx.x >> 6;
    const int l   = threadIdx.x & 63;
    const int sub = l >> 4;      // row-within-4-chunk
    const int m16 = l & 15;      // permuted col group: cols' 4*m16..+3
    for (int n = blockIdx.x * 4 + w; n < NN; n += gridDim.x * 4) {
        int ja = (n == 0) ? 0 : off[n - 1];
        int jb = off[n];
        int ka = off[NN + n - 1];   // n==0 -> off[NN-1] = start of k-region
        int kb = off[NN + n];
        float s0 = 0.f, s1 = 0.f, s2 = 0.f, s3 = 0.f;
        float t0 = 0.f, t1 = 0.f, t2 = 0.f, t3 = 0.f;
        for (int p = ja + sub; p < jb; p += 4) {
            f16x4 v = *(const f16x4*)(msg + (size_t)p * 64 + m16 * 4);
            s0 += (float)v[0]; s1 += (float)v[1];
            s2 += (float)v[2]; s3 += (float)v[3];
        }
        for (int p = ka + sub; p < kb; p += 4) {
            f16x4 v = *(const f16x4*)(msg + (size_t)p * 64 + m16 * 4);
            t0 += (float)v[0]; t1 += (float)v[1];
            t2 += (float)v[2]; t3 += (float)v[3];
        }
        s0 += __shfl_xor(s0, 16); s0 += __shfl_xor(s0, 32);
        s1 += __shfl_xor(s1, 16); s1 += __shfl_xor(s1, 32);
        s2 += __shfl_xor(s2, 16); s2 += __shfl_xor(s2, 32);
        s3 += __shfl_xor(s3, 16); s3 += __shfl_xor(s3, 32);
        t0 += __shfl_xor(t0, 16); t0 += __shfl_xor(t0, 32);
        t1 += __shfl_xor(t1, 16); t1 += __shfl_xor(t1, 32);
        t2 += __shfl_xor(t2, 16); t2 += __shfl_xor(t2, 32);
        t3 += __shfl_xor(t3, 16); t3 += __shfl_xor(t3, 32);
        if (sub == 0) {
            float rj = 1.0f / fmaxf((float)(jb - ja), 1.0f);
            float rk = 1.0f / fmaxf((float)(kb - ka), 1.0f);
            float* o = out + (size_t)n * 64;
            o[m16]      = s0 * rj + t0 * rk;   // col' 4m+nt <-> true col 16nt+m
            o[16 + m16] = s1 * rj + t1 * rk;
            o[32 + m16] = s2 * rj + t2 * rk;
            o[48 + m16] = s3 * rj + t3 * rk;
        }
    }
}

// ============================ launch ============================

extern "C" void kernel_launch(void* const* d_in, const int* in_sizes, int n_in,
                              void* d_out, int out_size, void* d_ws, size_t ws_size,
                              hipStream_t stream) {
    (void)in_sizes; (void)n_in; (void)out_size;

    const float* x     = (const float*)d_in[0];
    const float* pos   = (const float*)d_in[1];
    const int*   qidx  = (const int*)d_in[2];
    const float* qattr = (const float*)d_in[3];
    const float* gamma = (const float*)d_in[4];
    const float* beta  = (const float*)d_in[5];
    const float* w1    = (const float*)d_in[6];
    const float* b1    = (const float*)d_in[7];
    const float* w2    = (const float*)d_in[8];
    const float* b2    = (const float*)d_in[9];
    const float* w3    = (const float*)d_in[10];
    const float* b3    = (const float*)d_in[11];
    const float* w_out = (const float*)d_in[12];
    float* out = (float*)d_out;

    size_t o = 0;
    auto alloc = [&](size_t bytes) { size_t r = o; o = (o + bytes + 255) & ~(size_t)255; return r; };
    char* W = (char*)d_ws;
    f16*    msg    = (f16*)   (W + alloc((size_t)2 * ND * 64 * sizeof(f16)));   // 244 MiB
    int*    slot_j = (int*)   (W + alloc((size_t)ND * sizeof(int)));
    int*    slot_k = (int*)   (W + alloc((size_t)ND * sizeof(int)));
    int*    off    = (int*)   (W + alloc((size_t)NCNT * sizeof(int)));
    int*    bsum   = (int*)   (W + alloc((size_t)NBLK_SCAN * sizeof(int)));
    float2* sqt    = (float2*)(W + alloc((size_t)NN * sizeof(float2)));         // 0.76 MiB
    __bf16* w1h    = (__bf16*)(W + alloc((size_t)64 * K1P * sizeof(__bf16)));
    __bf16* w1l    = (__bf16*)(W + alloc((size_t)64 * K1P * sizeof(__bf16)));
    __bf16* w2h    = (__bf16*)(W + alloc((size_t)64 * 64 * sizeof(__bf16)));
    __bf16* w2l    = (__bf16*)(W + alloc((size_t)64 * 64 * sizeof(__bf16)));
    __bf16* w3h    = (__bf16*)(W + alloc((size_t)64 * 64 * sizeof(__bf16)));
    __bf16* w3l    = (__bf16*)(W + alloc((size_t)64 * 64 * sizeof(__bf16)));
    float*  c1     = (float*) (W + alloc((size_t)64 * sizeof(float)));
    float*  d1     = (float*) (W + alloc((size_t)64 * sizeof(float)));
    float*  b3f    = (float*) (W + alloc((size_t)64 * sizeof(float)));
    if (ws_size < o) return;   // ~253.4 MiB — within the R2-proven ws bound

    // prep
    prep_sq<<<NN / 4, 256, 0, stream>>>(x, sqt);
    prep_all<<<58, 256, 0, stream>>>(w1, b1, w2, w3, b3, w_out, gamma, beta,
                                     w1h, w1l, c1, d1, w2h, w2l, w3h, w3l, b3f);

    // counting sort
    hipMemsetAsync(off, 0, (size_t)NCNT * sizeof(int), stream);
    count_kernel<<<(ND + 255) / 256, 256, 0, stream>>>(qidx, off);
    scan1<<<NBLK_SCAN, 256, 0, stream>>>(off, bsum);
    scan2<<<1, 128, 0, stream>>>(bsum);
    scan3<<<NBLK_SCAN, 256, 0, stream>>>(off, bsum);
    fill_kernel<<<(ND + 255) / 256, 256, 0, stream>>>(qidx, off, slot_j, slot_k);

    // edge MLP (64 edges/wave) -> msg (dual sorted-slot scatter)
    edge_mlp_mfma<<<(ND / 64 + 3) / 4, 256, 0, stream>>>(x, sqt, pos, qidx, qattr,
                                                         w1h, w1l, c1, d1,
                                                         w2h, w2l, b2, w3h, w3l, b3f,
                                                         slot_j, slot_k, msg);
    // node aggregation (sequential segmented mean)
    node_out<<<4096, 256, 0, stream>>>(msg, off, out);
}